// Round 14
// baseline (59.280 us; speedup 1.0000x reference)
//
#include <hip/hip_runtime.h>
#include <math.h>

#define I_DIM 1024
#define S_DIM 512
#define O_DIM 1024
#define T_DIM 2048
#define B_SZ 4
#define M_ROWS (B_SZ * T_DIM)   // 8192
#define EPSF 1e-6f

// scan chunking: chunk length == GEMM BM (64)
#define CL 64
#define NCH 32   // NCH*CL == T_DIM

typedef _Float16 f16;
typedef __attribute__((ext_vector_type(8))) _Float16 f16x8;
typedef __attribute__((ext_vector_type(2))) _Float16 f16x2;
typedef __attribute__((ext_vector_type(4))) float f32x4;

__device__ __forceinline__ unsigned short f2h_bits(float f) {
    _Float16 h = (_Float16)f;
    return __builtin_bit_cast(unsigned short, h);
}

// async 16B global -> LDS (wave-uniform LDS base + lane*16 -> LINEAR dest only)
__device__ __forceinline__ void load16_lds(const void* g, void* l) {
    __builtin_amdgcn_global_load_lds((const __attribute__((address_space(1))) void*)g,
                                     (__attribute__((address_space(3))) void*)l,
                                     16, 0, 0);
}

// ---------------------------------------------------------------------------
// prep: RMSNorm->u16 (rs folded)  +  B^T (dts,nw folded)  +  C^T.
//   blocks [0, 8192)    : u16[m,i] = f16( u[m,i] * rsqrt(mean u^2 + eps) )
//   blocks [8192, 8704) : Bt16[s,i] = f16( B[i,s] * sigmoid(dt[s]) * nw[i] )
//   blocks [8704, 9216) : Ct16[o,s] = f16( C[s,o] )
// Streaming + latency-tolerant; keeps the fp32 u stream OUT of gemm1's loop
// (r13 lesson: the fp32 u K-loop stream thrashed L2 at 4MB/XCD panel
// footprint and pinned gemm1 at ~41us regardless of pipeline depth).
// ---------------------------------------------------------------------------
__global__ __launch_bounds__(256)
void prep(const float* __restrict__ u, const float* __restrict__ nw,
          unsigned short* __restrict__ u16,
          const float* __restrict__ Bmat, const float* __restrict__ dt,
          unsigned short* __restrict__ Bt16,
          const float* __restrict__ Cmat, unsigned short* __restrict__ Ct16) {
    __shared__ float tile[32][33];
    const int t = threadIdx.x;
    const int bx = blockIdx.x;

    if (bx < M_ROWS) {
        float4 v = ((const float4*)(u + (size_t)bx * I_DIM))[t];
        float ss = v.x * v.x + v.y * v.y + v.z * v.z + v.w * v.w;
        #pragma unroll
        for (int off = 32; off > 0; off >>= 1) ss += __shfl_down(ss, off, 64);
        if ((t & 63) == 0) tile[0][t >> 6] = ss;
        __syncthreads();
        if (t == 0)
            tile[0][0] = rsqrtf((tile[0][0] + tile[0][1] + tile[0][2] + tile[0][3])
                                * (1.0f / I_DIM) + EPSF);
        __syncthreads();
        const float rs = tile[0][0];
        ushort4 o;
        o.x = f2h_bits(v.x * rs);
        o.y = f2h_bits(v.y * rs);
        o.z = f2h_bits(v.z * rs);
        o.w = f2h_bits(v.w * rs);
        ((ushort4*)(u16 + (size_t)bx * I_DIM))[t] = o;
    } else if (bx < M_ROWS + 512) {
        const int tb = bx - M_ROWS;
        const int bs = (tb & 15) * 32;   // s block
        const int bi = (tb >> 4) * 32;   // i block
        const int tx = t & 31, ty = t >> 5;
        #pragma unroll
        for (int i = ty; i < 32; i += 8)
            tile[i][tx] = Bmat[(size_t)(bi + i) * S_DIM + bs + tx];
        __syncthreads();
        const float w = nw[bi + tx];
        #pragma unroll
        for (int i = ty; i < 32; i += 8) {
            const int s = bs + i;
            const float dts = 1.0f / (1.0f + expf(-dt[s]));
            Bt16[(size_t)s * I_DIM + bi + tx] = f2h_bits(tile[tx][i] * dts * w);
        }
    } else {
        const int tb = bx - M_ROWS - 512;
        const int bo = (tb & 31) * 32;   // o block
        const int bs = (tb >> 5) * 32;   // s block
        const int tx = t & 31, ty = t >> 5;
        #pragma unroll
        for (int i = ty; i < 32; i += 8)
            tile[i][tx] = Cmat[(size_t)(bs + i) * O_DIM + bo + tx];
        __syncthreads();
        #pragma unroll
        for (int i = ty; i < 32; i += 8)
            Ct16[(size_t)(bo + i) * S_DIM + bs + tx] = f2h_bits(tile[tx][i]);
    }
}

// ---------------------------------------------------------------------------
// GEMM1 + fused scan pass-1.  up = u16 @ Bt^T.  PURE gl_lds staging, no
// reg-staging, no ds_write, no lgkm in the K-loop (ablates r13's suspects).
// Depth-4: 5 LDS slots (60 KB -> 2 blocks/CU), 3 gl_lds/step (A 1 + B 2),
// stage kt+4 after the barrier, steady vmcnt(9) (tiles kt+1..kt+3 = 9 ops
// stay in flight), single barrier/iter, fully unrolled (static slots+imm).
// Both-sides XOR chunk swizzle (r8-proven): src chunk (t&3)^((t>>3)&3),
// read chunk kg^((lr>>1)&3) -> 2-way banks.
// u16 panel footprint per XCD: 16 panels x 128 KB = 2 MB -> L2-fits with Bt.
// ---------------------------------------------------------------------------
__global__ __launch_bounds__(256)
void gemm1_chfin(const f16* __restrict__ A, const f16* __restrict__ Bt,
                 f16* __restrict__ up, float* __restrict__ chlast,
                 const float* __restrict__ dt, const float* __restrict__ Avec) {
    constexpr int K = I_DIM, N = S_DIM, NK = K / 32;   // 32 k-steps
    __shared__ f16 As[5][64 * 32];    // 5 x 4 KB
    __shared__ f16 Bs[5][128 * 32];   // 5 x 8 KB
    const int t = threadIdx.x;

    // XCD swizzle (512 = 8*64): 4 consecutive logical bids share an A panel
    int bid = blockIdx.x;
    bid = (bid & 7) * 64 + (bid >> 3);
    const int n0 = (bid & 3) * 128;       // 4 n-blocks
    const int m0 = (bid >> 2) * 64;       // 128 m-blocks
    const int wid = t >> 6, lane = t & 63;
    const int wn = wid * 32, lr = lane & 15, kg = lane >> 4;

    // source-side chunk swizzle (matches read side)
    const int swch = (t & 3) ^ ((t >> 3) & 3);
    const f16* aptr = A + (size_t)(m0 + (t >> 2)) * K + swch * 8;
    const f16* bptr = Bt + (size_t)(n0 + (t >> 2)) * K + swch * 8;
    const int rchunk = (kg ^ ((lr >> 1) & 3)) * 8;

    f32x4 acc[4][2];
    #pragma unroll
    for (int i = 0; i < 4; ++i)
        #pragma unroll
        for (int j = 0; j < 2; ++j) acc[i][j] = (f32x4){0.f, 0.f, 0.f, 0.f};

    auto stage = [&](int kt, int slot) {
        load16_lds(aptr + kt * 32, &As[slot][t * 8]);
        load16_lds(bptr + kt * 32, &Bs[slot][t * 8]);
        load16_lds(bptr + (size_t)64 * K + kt * 32, &Bs[slot][2048 + t * 8]);
    };

    // prologue: tiles 0..3 in flight (12 ops)
    stage(0, 0); stage(1, 1); stage(2, 2); stage(3, 3);

    #pragma unroll
    for (int kt = 0; kt < NK; ++kt) {
        if (kt < NK - 3)       asm volatile("s_waitcnt vmcnt(9)");   // tile kt landed
        else if (kt == NK - 3) asm volatile("s_waitcnt vmcnt(6)");
        else if (kt == NK - 2) asm volatile("s_waitcnt vmcnt(3)");
        else                   asm volatile("s_waitcnt vmcnt(0)");
        __builtin_amdgcn_s_barrier();          // all waves: tile kt in LDS;
        __builtin_amdgcn_sched_barrier(0);     // prev iter's reads retired
        if (kt + 4 < NK) stage(kt + 4, (kt + 4) % 5);   // into slot read 4 iters ago

        const int slot = kt % 5;
        f16x8 af[4], bf[2];
        #pragma unroll
        for (int m = 0; m < 4; ++m)
            af[m] = *(const f16x8*)&As[slot][(m * 16 + lr) * 32 + rchunk];
        #pragma unroll
        for (int n = 0; n < 2; ++n)
            bf[n] = *(const f16x8*)&Bs[slot][(wn + n * 16 + lr) * 32 + rchunk];
        __builtin_amdgcn_s_setprio(1);
        #pragma unroll
        for (int m = 0; m < 4; ++m)
            #pragma unroll
            for (int n = 0; n < 2; ++n)
                acc[m][n] = __builtin_amdgcn_mfma_f32_16x16x32_f16(af[m], bf[n], acc[m][n], 0, 0, 0);
        __builtin_amdgcn_s_setprio(0);
    }

    // epilogue: up (f16) + fused chunk-final (fp32)
    // C/D layout: col = lane&15, row = (lane>>4)*4 + reg
    const int cb = m0 >> 11;               // batch
    const int cc = (m0 >> 6) & (NCH - 1);  // chunk
    #pragma unroll
    for (int n = 0; n < 2; ++n) {
        const int col = n0 + wn + n * 16 + lr;
        const float dts = 1.0f / (1.0f + expf(-dt[col]));
        const float e = dts * fabsf(Avec[col]);
        const float ainv = expf(e);        // a^-1
        float partial = 0.f;
        #pragma unroll
        for (int m = 0; m < 4; ++m) {
            const int row = m * 16 + kg * 4;
            float wgt = expf(-e * (float)(63 - row));   // a^(63-row)
            #pragma unroll
            for (int j = 0; j < 4; ++j) {
                const float val = acc[m][n][j];
                up[(size_t)(m0 + row + j) * N + col] = (_Float16)val;
                partial = fmaf(wgt, val, partial);
                wgt *= ainv;
            }
        }
        partial += __shfl_xor(partial, 16, 64);
        partial += __shfl_xor(partial, 32, 64);
        if (kg == 0)
            chlast[(size_t)(cb * NCH + cc) * S_DIM + col] = partial;
    }
}

// ---------------------------------------------------------------------------
// GEMM2 fused with scan pass-2:  y = x @ C + D,  x_t = a*x_{t-1} + up_t.
// (r12 version, ~10 us: K-loop touches only L2-resident Ct16; up16
// prefetched as 64 independent loads up front.)  LDS exactly 80 KB.
// ---------------------------------------------------------------------------
__global__ __launch_bounds__(256)
void gemm2_scan(const f16* __restrict__ upb, const float* __restrict__ chlast,
                const f16* __restrict__ Ct, const float* __restrict__ Dvec,
                const float* __restrict__ dt, const float* __restrict__ Avec,
                float* __restrict__ y, float* __restrict__ xlast) {
    constexpr int K = S_DIM, N = O_DIM, NK = K / 32;   // 16 k-steps
    __shared__ __align__(16) unsigned char As[64 * 1024];   // 64 KB x-tile
    __shared__ f16 Bs[2][128 * 32];                         // 16 KB
    const int t = threadIdx.x;

    int bid = blockIdx.x;                 // grid = 1024
    bid = (bid & 7) * 128 + (bid >> 3);
    const int n0 = (bid & 7) * 128;       // 8 n-blocks
    const int m0 = (bid >> 3) * 64;       // 128 m-blocks (= b*32 + chunk)
    const int wid = t >> 6, lane = t & 63;
    const int wn = wid * 32, lr = lane & 15, kg = lane >> 4;

    // stage B(0) early (pre-swizzled source)
    const int srcswz = ((t & 3) ^ ((t >> 3) & 3)) * 8;
    const f16* bptr = Ct + (size_t)(n0 + (t >> 2)) * K + srcswz;
    auto stageB = [&](int kt, int slot) {
        load16_lds(bptr + kt * 32, &Bs[slot][t * 8]);
        load16_lds(bptr + (size_t)64 * K + kt * 32, &Bs[slot][2048 + t * 8]);
    };
    stageB(0, 0);
    const int rchunk = (kg ^ ((lr >> 1) & 3)) * 8;

    // ---- issue up-chunk loads FIRST (64 independent dwords in flight) ----
    const unsigned* up32 = (const unsigned*)upb;
    const size_t ub = (size_t)m0 * 256 + t;
    unsigned v[CL];
    #pragma unroll
    for (int j = 0; j < CL; ++j) v[j] = up32[ub + (size_t)j * 256];

    // ---- carry prefix over chunk finals (overlaps up-load flight) ----
    const int cc = (m0 >> 6) & (NCH - 1);
    const int cb = m0 >> 11;
    const int s0 = 2 * t;
    const float dts0 = 1.0f / (1.0f + expf(-dt[s0]));
    const float dts1 = 1.0f / (1.0f + expf(-dt[s0 + 1]));
    const float ab0 = fabsf(Avec[s0]), ab1 = fabsf(Avec[s0 + 1]);
    const float g0 = expf(-dts0 * ab0);
    const float g1 = expf(-dts1 * ab1);
    const float gCL0 = expf(-dts0 * ab0 * (float)CL);
    const float gCL1 = expf(-dts1 * ab1 * (float)CL);
    const float2* ch = (const float2*)chlast;
    float cy0 = 0.f, cy1 = 0.f;
    {
        int j = 0;
        for (; j + 4 <= cc; j += 4) {
            float2 f0 = ch[(size_t)(cb * NCH + j + 0) * 256 + t];
            float2 f1 = ch[(size_t)(cb * NCH + j + 1) * 256 + t];
            float2 f2 = ch[(size_t)(cb * NCH + j + 2) * 256 + t];
            float2 f3 = ch[(size_t)(cb * NCH + j + 3) * 256 + t];
            cy0 = fmaf(gCL0, cy0, f0.x); cy1 = fmaf(gCL1, cy1, f0.y);
            cy0 = fmaf(gCL0, cy0, f1.x); cy1 = fmaf(gCL1, cy1, f1.y);
            cy0 = fmaf(gCL0, cy0, f2.x); cy1 = fmaf(gCL1, cy1, f2.y);
            cy0 = fmaf(gCL0, cy0, f3.x); cy1 = fmaf(gCL1, cy1, f3.y);
        }
        for (; j < cc; ++j) {
            float2 f = ch[(size_t)(cb * NCH + j) * 256 + t];
            cy0 = fmaf(gCL0, cy0, f.x);
            cy1 = fmaf(gCL1, cy1, f.y);
        }
    }

    // ---- scan + swizzled LDS write ----
    float x0 = cy0, x1 = cy1;
    #pragma unroll
    for (int j = 0; j < CL; ++j) {
        f16x2 h = __builtin_bit_cast(f16x2, v[j]);
        x0 = fmaf(g0, x0, (float)h.x);
        x1 = fmaf(g1, x1, (float)h.y);
        f16x2 o; o.x = (_Float16)x0; o.y = (_Float16)x1;
        v[j] = __builtin_bit_cast(unsigned, o);
    }
    #pragma unroll
    for (int j = 0; j < CL; ++j)
        *(unsigned*)&As[j * 1024 + ((t * 4) ^ ((j & 7) << 4))] = v[j];
    if (cc == NCH - 1)
        ((float2*)xlast)[cb * 256 + t] = make_float2(x0, x1);   // dup across n-blocks, same value
    __syncthreads();   // one-time full drain: scan ds_writes + B(0) staging

    // ---- K-loop: A resident in LDS, B double-buffered, counted vmcnt ----
    f32x4 acc[4][2];
    #pragma unroll
    for (int i = 0; i < 4; ++i)
        #pragma unroll
        for (int j = 0; j < 2; ++j) acc[i][j] = (f32x4){0.f, 0.f, 0.f, 0.f};

    const int swz = (lr & 7) << 4;        // row&7 == lr&7 for row = m*16+lr
    for (int kt = 0; kt < NK; ++kt) {
        const int cur = kt & 1;
        if (kt + 1 < NK) {
            stageB(kt + 1, cur ^ 1);
            asm volatile("s_waitcnt vmcnt(2)");   // B[kt] done; B[kt+1] in flight
        } else {
            asm volatile("s_waitcnt vmcnt(0)");
        }
        __builtin_amdgcn_s_barrier();
        __builtin_amdgcn_sched_barrier(0);

        f16x8 af[4], bf[2];
        #pragma unroll
        for (int m = 0; m < 4; ++m)
            af[m] = *(const f16x8*)&As[(m * 16 + lr) * 1024 + ((kt * 64 + kg * 16) ^ swz)];
        #pragma unroll
        for (int n = 0; n < 2; ++n)
            bf[n] = *(const f16x8*)&Bs[cur][(wn + n * 16 + lr) * 32 + rchunk];
        __builtin_amdgcn_s_setprio(1);
        #pragma unroll
        for (int m = 0; m < 4; ++m)
            #pragma unroll
            for (int n = 0; n < 2; ++n)
                acc[m][n] = __builtin_amdgcn_mfma_f32_16x16x32_f16(af[m], bf[n], acc[m][n], 0, 0, 0);
        __builtin_amdgcn_s_setprio(0);
        __builtin_amdgcn_s_barrier();    // Bs[cur] reads done before restage
    }

    // epilogue: y = acc + D
    #pragma unroll
    for (int n = 0; n < 2; ++n) {
        const int col = n0 + wn + n * 16 + lr;
        const float dv = Dvec[col];
        #pragma unroll
        for (int m = 0; m < 4; ++m) {
            const int row = m0 + m * 16 + kg * 4;
            #pragma unroll
            for (int j = 0; j < 4; ++j)
                y[(size_t)(row + j) * N + col] = acc[m][n][j] + dv;
        }
    }
}

// ---------------------------------------------------------------------------
extern "C" void kernel_launch(void* const* d_in, const int* in_sizes, int n_in,
                              void* d_out, int out_size, void* d_ws, size_t ws_size,
                              hipStream_t stream) {
    const float* u    = (const float*)d_in[0];   // [B,T,I]
    const float* dt   = (const float*)d_in[1];   // [S]
    const float* Avec = (const float*)d_in[2];   // [S]
    const float* Bmat = (const float*)d_in[3];   // [I,S]
    const float* Cmat = (const float*)d_in[4];   // [S,O]
    const float* Dvec = (const float*)d_in[5];   // [O]
    const float* nw   = (const float*)d_in[6];   // [I]

    float* y     = (float*)d_out;                      // [B,T,O] fp32
    float* xlast = y + (size_t)M_ROWS * O_DIM;         // [B,S]   fp32

    // workspace (~27.5 MB)
    char* w = (char*)d_ws;
    unsigned short* u16    = (unsigned short*)(w);               // [8192,1024] f16 (rs folded)
    f16*            up16   = (f16*)(w + 16777216);               // [8192,512]  f16
    unsigned short* Bt16   = (unsigned short*)(w + 25165824);    // [512,1024]  f16 (dts,nw folded)
    unsigned short* Ct16   = (unsigned short*)(w + 26214400);    // [1024,512]  f16
    float*          chlast = (float*)(w + 27262976);             // [B,NCH,S]   fp32

    // 1. prep: rmsnorm->u16 + weight transposes
    prep<<<M_ROWS + 512 + 512, 256, 0, stream>>>(u, nw, u16, Bmat, dt, Bt16, Cmat, Ct16);

    // 2. GEMM1 (+chunk finals): up16 = u16 @ Bt, chlast
    gemm1_chfin<<<512, 256, 0, stream>>>((const f16*)u16, (const f16*)Bt16,
                                         up16, chlast, dt, Avec);

    // 3. GEMM2 (+carry +scan): y, xlast
    gemm2_scan<<<1024, 256, 0, stream>>>(up16, chlast, (const f16*)Ct16, Dvec,
                                         dt, Avec, y, xlast);
}